// Round 20
// baseline (765.279 us; speedup 1.0000x reference)
//
#include <hip/hip_runtime.h>
#include <hip/hip_bf16.h>

#define BATCH 8
#define N1 4096
#define N2 2048
#define HID 64
#define KNN 8
#define INDIM 10

using u64 = unsigned long long;
using bf16 = __hip_bfloat16;
typedef __attribute__((ext_vector_type(8))) short short8;
typedef __attribute__((ext_vector_type(4))) float f32x4;

// Scratch in static device memory (~115 MB): d_ws size is not guaranteed.
// Every buffer is fully rewritten each call (or re-initialized by init_kernel).
__device__ __align__(256) float    g_h1[BATCH * N1 * HID];
__device__ __align__(256) float    g_h2[BATCH * N2 * HID];
__device__ __align__(256) float    g_x2n[BATCH * N1];
__device__ __align__(256) float    g_x2n2[BATCH * N2];
__device__ __align__(256) int      g_nbr[BATCH * N1 * KNN];
__device__ __align__(256) float    g_uu[BATCH * N1 * 96];
__device__ __align__(256) float    g_vv[BATCH * N1 * 96];
__device__ __align__(256) unsigned g_ek1[BATCH * N1 * HID];
__device__ __align__(256) unsigned g_ek2[BATCH * N2 * HID];
// 3-way bf16 split of h in MFMA FRAGMENT-MAJOR layout (kNN):
// [tile16][chunk(2)][q(4)][c(16)][j(8)] shorts; node i=tile*16+c.
__device__ __align__(256) short    g_f1[BATCH * N1 * HID];
__device__ __align__(256) short    g_f2[BATCH * N1 * HID];
__device__ __align__(256) short    g_f3[BATCH * N1 * HID];
// frag-major f32 copies of u,v for edge MFMA A-prep:
// [tile16][kc(3)][q(4)][c(16)][j(8)] floats, node = tile*16+c, kk=kc*32+q*8+j.
__device__ __align__(256) float    g_uf[BATCH * N1 * 96];
__device__ __align__(256) float    g_vf[BATCH * N1 * 96];
// 2-way bf16 split W2 fragments: [level][no(4)][kc(3)][lane(64)][j(8)]
__device__ __align__(256) short    g_wf1[2 * 4 * 3 * 64 * 8];
__device__ __align__(256) short    g_wf2[2 * 4 * 3 * 64 * 8];

__device__ __forceinline__ float eluf(float x) { return x > 0.f ? x : __expf(x) - 1.f; }
// order-isomorphic float->u32 encoding: a<b  <=>  enc(a)<enc(b) (unsigned)
__device__ __forceinline__ unsigned encf(float f) {
  unsigned u = __float_as_uint(f);
  return (u & 0x80000000u) ? ~u : (u | 0x80000000u);
}
__device__ __forceinline__ float decf(unsigned k) {
  unsigned u = (k & 0x80000000u) ? (k & 0x7FFFFFFFu) : ~k;
  return __uint_as_float(u);
}
// encf(-1.0f): ELU outputs are strictly > -1 => legal max-identity.
#define ENC_NEG1 0x407FFFFFu
__device__ __forceinline__ unsigned enc_safe(float v) {
  if (!(v == v)) return ENC_NEG1;
  return encf(v);
}
__device__ __forceinline__ float dec_safe(unsigned k) {
  float v = decf(k);
  if (!(v == v)) return -1.0f;
  return fminf(fmaxf(v, -3.0e38f), 3.0e38f);
}
// 3-way bf16 split: v ~= b1 + b2 + b3 (error ~2^-25 relative)
__device__ __forceinline__ void split3(float v, short& b1, short& b2, short& b3) {
  bf16 x1 = __float2bfloat16(v);
  float r1 = v - __bfloat162float(x1);
  bf16 x2 = __float2bfloat16(r1);
  float r2 = r1 - __bfloat162float(x2);
  bf16 x3 = __float2bfloat16(r2);
  b1 = *(short*)&x1; b2 = *(short*)&x2; b3 = *(short*)&x3;
}
// 2-way bf16 split
__device__ __forceinline__ void split2(float v, short& b1, short& b2) {
  bf16 x1 = __float2bfloat16(v);
  float r1 = v - __bfloat162float(x1);
  bf16 x2 = __float2bfloat16(r1);
  b1 = *(short*)&x1; b2 = *(short*)&x2;
}
// write one node's 64 splits into kNN fragment-major layout
__device__ __forceinline__ void store_frags(int node, const short* s1,
                                            const short* s2, const short* s3) {
  size_t tb = ((size_t)(node >> 4)) * 1024 + (node & 15) * 8;
#pragma unroll
  for (int chunk = 0; chunk < 2; ++chunk) {
#pragma unroll
    for (int q = 0; q < 4; ++q) {
      size_t a = tb + chunk * 512 + q * 128;
      int k = chunk * 32 + q * 8;
      *(short8*)(g_f1 + a) = *(const short8*)(s1 + k);
      *(short8*)(g_f2 + a) = *(const short8*)(s2 + k);
      *(short8*)(g_f3 + a) = *(const short8*)(s3 + k);
    }
  }
}
// elu(a+b) for 8 floats -> 2-way split short8 frags
__device__ __forceinline__ void tv_frag(float4 a0, float4 a1, float4 b0,
                                        float4 b1, short8& s1, short8& s2) {
  float v[8] = {a0.x + b0.x, a0.y + b0.y, a0.z + b0.z, a0.w + b0.w,
                a1.x + b1.x, a1.y + b1.y, a1.z + b1.z, a1.w + b1.w};
#pragma unroll
  for (int e = 0; e < 8; ++e) {
    float t = eluf(v[e]);
    short p1, p2;
    split2(t, p1, p2);
    s1[e] = p1; s2[e] = p2;
  }
}

// ---------------- init the scatter-max accumulators --------------------------
__global__ __launch_bounds__(256) void init_kernel() {
  int t = blockIdx.x * 256 + threadIdx.x;
  uint4 z = make_uint4(ENC_NEG1, ENC_NEG1, ENC_NEG1, ENC_NEG1);
  const int n1 = BATCH * N1 * HID / 4;
  if (t < n1) ((uint4*)g_ek1)[t] = z;
  else ((uint4*)g_ek2)[t - n1] = z;
}

// ---------------- W2 -> 2-way-split MFMA B-fragments (once per launch) -------
__global__ __launch_bounds__(256) void wfrag_kernel(const float* __restrict__ w1,
                                                    const float* __restrict__ w2) {
  int level = blockIdx.x;
  const float* w = level ? w2 : w1;
  for (int idx = threadIdx.x; idx < 6144; idx += 256) {
    int no = idx / 1536;
    int rem = idx - no * 1536;
    int kc = rem / 512;
    int rem2 = rem - kc * 512;
    int lane = rem2 >> 3;
    int j = rem2 & 7;
    int k = kc * 32 + (lane >> 4) * 8 + j;
    int o = no * 16 + (lane & 15);
    short b1, b2;
    split2(w[k * 64 + o], b1, b2);
    g_wf1[level * 6144 + idx] = b1;
    g_wf2[level * 6144 + idx] = b2;
  }
}

// ---------------- input MLP: x*norm -> 32 (elu) -> 64 (elu) + |h|^2 + splits -
__global__ __launch_bounds__(256) void input_mlp(
    const float* __restrict__ x, const float* __restrict__ norm,
    const float* __restrict__ w1g, const float* __restrict__ b1g,
    const float* __restrict__ w2g, const float* __restrict__ b2g) {
  __shared__ float sw1[320], sb1[32], sw2[2048], sb2[64], snorm[INDIM];
  int t = threadIdx.x;
  for (int q = t; q < 320; q += 256) sw1[q] = w1g[q];
  for (int q = t; q < 2048; q += 256) sw2[q] = w2g[q];
  if (t < 32) sb1[t] = b1g[t];
  if (t < 64) sb2[t] = b2g[t];
  if (t < INDIM) snorm[t] = norm[t];
  __syncthreads();
  int node = blockIdx.x * 256 + t;  // < BATCH*N1
  float xv[INDIM];
#pragma unroll
  for (int d = 0; d < INDIM; ++d)
    xv[d] = x[(size_t)node * INDIM + d] * snorm[d];
  float t1[32];
#pragma unroll
  for (int c = 0; c < 32; ++c) {
    float acc = sb1[c];
#pragma unroll
    for (int d = 0; d < INDIM; ++d) acc += xv[d] * sw1[d * 32 + c];
    t1[c] = eluf(acc);
  }
  float* hr = g_h1 + (size_t)node * HID;
  float sq = 0.f;
  short s1l[HID], s2l[HID], s3l[HID];
#pragma unroll
  for (int c = 0; c < HID; ++c) {
    float acc = sb2[c];
#pragma unroll
    for (int d = 0; d < 32; ++d) acc += t1[d] * sw2[d * HID + c];
    float v = eluf(acc);
    hr[c] = v;
    sq += v * v;
    split3(v, s1l[c], s2l[c], s3l[c]);
  }
  store_frags(node, s1l, s2l, s3l);
  g_x2n[node] = sq;
}

// ---------------- MFMA Gram-matrix kNN (k=8), u32-key bubble selection -------
// r17's best-known config (220us): 256-thread blocks, unsplit columns.
// Selection: key32 = (encf(dd)&0xFFFFFF00)|ct, unconditional 8-step
// v_min/v_max bubble; 16-lane exact merge via LDS (u64-lifted, tie->lowest j).
template <int LEVEL>
__global__ __launch_bounds__(256, 1) void knn_kernel() {
  constexpr int n = LEVEL ? N2 : N1;
  __shared__ unsigned lm[4][16][16][KNN];  // 32 KB
  int b = blockIdx.x & 7;             // XCD-friendly batch swizzle
  int rb = (blockIdx.x >> 3) * 64;    // block row base
  int t = threadIdx.x;
  int wv = t >> 6, lane = t & 63;
  int q = lane >> 4, c = lane & 15;
  int rbase = rb + wv * 16;           // wave's 16-row strip
  const float* __restrict__ x2b = (LEVEL ? g_x2n2 : g_x2n) + (size_t)b * n;
  size_t abase = ((size_t)((b * n + rbase) >> 4)) * 1024 + lane * 8;
  short8 A1a = *(const short8*)(g_f1 + abase);
  short8 A1b = *(const short8*)(g_f1 + abase + 512);
  short8 A2a = *(const short8*)(g_f2 + abase);
  short8 A2b = *(const short8*)(g_f2 + abase + 512);
  short8 A3a = *(const short8*)(g_f3 + abase);
  short8 A3b = *(const short8*)(g_f3 + abase + 512);
  float x2r[4];
#pragma unroll
  for (int r = 0; r < 4; ++r) x2r[r] = x2b[rbase + q * 4 + r];
  unsigned best[4][KNN];
#pragma unroll
  for (int r = 0; r < 4; ++r)
#pragma unroll
    for (int p = 0; p < KNN; ++p) best[r][p] = 0xFFFFFFFFu;
  size_t bb = ((size_t)(b * n) >> 4) * 1024 + lane * 8;
  for (int ct = 0; ct < n / 16; ++ct, bb += 1024) {
    int cb = ct * 16 + c;  // this lane's column
    short8 B1a = *(const short8*)(g_f1 + bb);
    short8 B1b = *(const short8*)(g_f1 + bb + 512);
    short8 B2a = *(const short8*)(g_f2 + bb);
    short8 B2b = *(const short8*)(g_f2 + bb + 512);
    short8 B3a = *(const short8*)(g_f3 + bb);
    short8 B3b = *(const short8*)(g_f3 + bb + 512);
    f32x4 acc0 = {0.f, 0.f, 0.f, 0.f};
    f32x4 acc1 = {0.f, 0.f, 0.f, 0.f};
    acc0 = __builtin_amdgcn_mfma_f32_16x16x32_bf16(A1a, B1a, acc0, 0, 0, 0);
    acc1 = __builtin_amdgcn_mfma_f32_16x16x32_bf16(A1b, B1b, acc1, 0, 0, 0);
    acc0 = __builtin_amdgcn_mfma_f32_16x16x32_bf16(A1a, B2a, acc0, 0, 0, 0);
    acc1 = __builtin_amdgcn_mfma_f32_16x16x32_bf16(A1b, B2b, acc1, 0, 0, 0);
    acc0 = __builtin_amdgcn_mfma_f32_16x16x32_bf16(A2a, B1a, acc0, 0, 0, 0);
    acc1 = __builtin_amdgcn_mfma_f32_16x16x32_bf16(A2b, B1b, acc1, 0, 0, 0);
    acc0 = __builtin_amdgcn_mfma_f32_16x16x32_bf16(A1a, B3a, acc0, 0, 0, 0);
    acc1 = __builtin_amdgcn_mfma_f32_16x16x32_bf16(A1b, B3b, acc1, 0, 0, 0);
    acc0 = __builtin_amdgcn_mfma_f32_16x16x32_bf16(A2a, B2a, acc0, 0, 0, 0);
    acc1 = __builtin_amdgcn_mfma_f32_16x16x32_bf16(A2b, B2b, acc1, 0, 0, 0);
    acc0 = __builtin_amdgcn_mfma_f32_16x16x32_bf16(A3a, B1a, acc0, 0, 0, 0);
    acc1 = __builtin_amdgcn_mfma_f32_16x16x32_bf16(A3b, B1b, acc1, 0, 0, 0);
    float x2c = x2b[cb];
#pragma unroll
    for (int r = 0; r < 4; ++r) {
      int i = rbase + q * 4 + r;
      float dd = x2r[r] + x2c - 2.f * (acc0[r] + acc1[r]);
      unsigned ck = (encf(dd) & 0xFFFFFF00u) | (unsigned)ct;
      ck = (cb == i) ? 0xFFFFFFFFu : ck;
#pragma unroll
      for (int p = 0; p < KNN; ++p) {
        unsigned nb = min(best[r][p], ck);
        ck = max(best[r][p], ck);
        best[r][p] = nb;
      }
    }
  }
#pragma unroll
  for (int r = 0; r < 4; ++r)
#pragma unroll
    for (int p = 0; p < KNN; ++p) lm[wv][q * 4 + r][c][p] = best[r][p];
  __syncthreads();
  if (t < 64) {
    int wv2 = t >> 4, r16 = t & 15;
    u64 fin[KNN];
#pragma unroll
    for (int p = 0; p < KNN; ++p) fin[p] = ((u64)lm[wv2][r16][0][p]) << 4;
    for (int c2 = 1; c2 < 16; ++c2) {
#pragma unroll
      for (int p = 0; p < KNN; ++p) {
        u64 ck = (((u64)lm[wv2][r16][c2][p]) << 4) | (unsigned)c2;
        if (ck < fin[KNN - 1]) {
#pragma unroll
          for (int p2 = 0; p2 < KNN; ++p2) {
            u64 ob = fin[p2];
            bool ex = ob < ck;
            fin[p2] = ex ? ob : ck;
            ck = ex ? ck : ob;
          }
        }
      }
    }
    int row = rb + wv2 * 16 + r16;
    int* ob = g_nbr + ((size_t)b * n + row) * KNN;
#pragma unroll
    for (int p = 0; p < KNN; ++p) {
      int j = (int)((fin[p] >> 4) & 255u) * 16 + (int)(fin[p] & 15u);
      ob[p] = j & (n - 1);
    }
  }
}

// ---------------- per-node u/v for EdgeConv layer-1 factorization ------------
__global__ __launch_bounds__(256) void uv_kernel(int level,
                                                 const float* __restrict__ w1g,
                                                 const float* __restrict__ b1g) {
  __shared__ float sw1[128 * 96];  // 48 KB
  __shared__ float sb1[96];
  int t = threadIdx.x;
  for (int q = t; q < 128 * 96; q += 256) sw1[q] = w1g[q];
  if (t < 96) sb1[t] = b1g[t];
  __syncthreads();
  const int n = level ? N2 : N1;
  const float* h = level ? g_h2 : g_h1;
  int b = blockIdx.x & 7;
  int nl = (blockIdx.x >> 3) * 64 + (t & 63);
  int c0 = (t >> 6) * 24;  // wave-uniform chunk
  size_t node = (size_t)b * n + nl;
  const float4* h4 = (const float4*)(h + node * HID);
  float hv[HID];
#pragma unroll
  for (int q = 0; q < 16; ++q) {
    float4 vv = h4[q];
    hv[4 * q] = vv.x; hv[4 * q + 1] = vv.y; hv[4 * q + 2] = vv.z; hv[4 * q + 3] = vv.w;
  }
  float ua[24], va[24];
#pragma unroll
  for (int c = 0; c < 24; ++c) { ua[c] = 0.f; va[c] = 0.f; }
  for (int d = 0; d < HID; ++d) {
    float hd = hv[d];
    const float* wt = sw1 + d * 96 + c0;        // wave-uniform -> broadcast
    const float* wb = sw1 + (HID + d) * 96 + c0;
#pragma unroll
    for (int c = 0; c < 24; ++c) {
      ua[c] += hd * wt[c];
      va[c] += hd * wb[c];
    }
  }
  float* ur = g_uu + node * 96 + c0;
  float* vr = g_vv + node * 96 + c0;
#pragma unroll
  for (int c = 0; c < 24; ++c) {
    float uval = ua[c] - va[c] + sb1[c0 + c];
    float vval = va[c];
    ur[c] = uval;
    vr[c] = vval;
    int kk = c0 + c;
    size_t fa = (node >> 4) * 1536 + (size_t)((kk >> 5) * 512 +
                ((kk >> 3) & 3) * 128 + (nl & 15) * 8 + (kk & 7));
    g_uf[fa] = uval;
    g_vf[fa] = vval;
  }
}

// ---------------- MFMA edge messages + max scatter (1-wave blocks) -----------
// Block = 1 wave = one 16-node frag tile. launch_bounds(64,2) caps combined
// VGPR+AGPR at 256 (need ~230) so 2 waves/SIMD become resident -- the r19
// (256,1) version sprawled registers and sat at 1-wave residency with its
// neighbor-gather latency (8 slots x 12 scattered float4 reads) unhidden.
template <int LEVEL>
__global__ __launch_bounds__(64, 2) void edge_kernel(
    const float* __restrict__ b2g) {
  constexpr int n = LEVEL ? N2 : N1;
  unsigned* ekey = LEVEL ? g_ek2 : g_ek1;
  int b = blockIdx.x & 7;  // XCD swizzle
  int lane = threadIdx.x;
  int q = lane >> 4, c = lane & 15;
  int base16 = (blockIdx.x >> 3) * 16;
  int node_c = base16 + c;
  const int* nbb = g_nbr + (size_t)b * n * KNN;
  const float* ub = g_uu + (size_t)b * n * 96;
  const float* vb = g_vv + (size_t)b * n * 96;
  size_t ftile = ((size_t)(b * n + base16) >> 4) * 1536;
  unsigned* eb = ekey + (size_t)b * n * HID;
  short8 W1f[4][3], W2f[4][3];
#pragma unroll
  for (int no = 0; no < 4; ++no)
#pragma unroll
    for (int kc = 0; kc < 3; ++kc) {
      int off = LEVEL * 6144 + ((no * 3 + kc) * 64 + lane) * 8;
      W1f[no][kc] = *(const short8*)(g_wf1 + off);
      W2f[no][kc] = *(const short8*)(g_wf2 + off);
    }
  float biasv[4];
#pragma unroll
  for (int no = 0; no < 4; ++no) biasv[no] = b2g[no * 16 + c];
  float macc[16];
#pragma unroll
  for (int e = 0; e < 16; ++e) macc[e] = -1.0f;
  for (int slot = 0; slot < KNN; ++slot) {
    int jn = nbb[(size_t)node_c * KNN + slot] & (n - 1);
    short8 t1[3], t2[3], r1[3], r2[3];
#pragma unroll
    for (int kc = 0; kc < 3; ++kc) {
      size_t fo = ftile + kc * 512 + lane * 8;
      float4 su0 = *(const float4*)(g_uf + fo);
      float4 su1 = *(const float4*)(g_uf + fo + 4);
      float4 sv0 = *(const float4*)(g_vf + fo);
      float4 sv1 = *(const float4*)(g_vf + fo + 4);
      size_t go = (size_t)jn * 96 + kc * 32 + q * 8;
      float4 gv0 = *(const float4*)(vb + go);
      float4 gv1 = *(const float4*)(vb + go + 4);
      float4 gu0 = *(const float4*)(ub + go);
      float4 gu1 = *(const float4*)(ub + go + 4);
      tv_frag(su0, su1, gv0, gv1, t1[kc], t2[kc]);   // fwd: u_i + v_j
      tv_frag(gu0, gu1, sv0, sv1, r1[kc], r2[kc]);   // rev: u_j + v_i
    }
    f32x4 aF[4], aR[4];
#pragma unroll
    for (int no = 0; no < 4; ++no) {
      aF[no] = (f32x4){0.f, 0.f, 0.f, 0.f};
      aR[no] = (f32x4){0.f, 0.f, 0.f, 0.f};
    }
#pragma unroll
    for (int no = 0; no < 4; ++no)
#pragma unroll
      for (int kc = 0; kc < 3; ++kc) {
        aF[no] = __builtin_amdgcn_mfma_f32_16x16x32_bf16(t1[kc], W1f[no][kc], aF[no], 0, 0, 0);
        aF[no] = __builtin_amdgcn_mfma_f32_16x16x32_bf16(t2[kc], W1f[no][kc], aF[no], 0, 0, 0);
        aF[no] = __builtin_amdgcn_mfma_f32_16x16x32_bf16(t1[kc], W2f[no][kc], aF[no], 0, 0, 0);
        aR[no] = __builtin_amdgcn_mfma_f32_16x16x32_bf16(r1[kc], W1f[no][kc], aR[no], 0, 0, 0);
        aR[no] = __builtin_amdgcn_mfma_f32_16x16x32_bf16(r2[kc], W1f[no][kc], aR[no], 0, 0, 0);
        aR[no] = __builtin_amdgcn_mfma_f32_16x16x32_bf16(r1[kc], W2f[no][kc], aR[no], 0, 0, 0);
      }
#pragma unroll
    for (int r = 0; r < 4; ++r) {
      int jr = nbb[(size_t)(base16 + q * 4 + r) * KNN + slot] & (n - 1);
#pragma unroll
      for (int no = 0; no < 4; ++no) {
        float mv = eluf(aR[no][r] + biasv[no]);
        atomicMax(&eb[(size_t)jr * HID + no * 16 + c], enc_safe(mv));
      }
    }
#pragma unroll
    for (int no = 0; no < 4; ++no)
#pragma unroll
      for (int r = 0; r < 4; ++r)
        macc[no * 4 + r] = fmaxf(macc[no * 4 + r], eluf(aF[no][r] + biasv[no]));
  }
#pragma unroll
  for (int r = 0; r < 4; ++r) {
    size_t ib = (size_t)(base16 + q * 4 + r) * HID;
#pragma unroll
    for (int no = 0; no < 4; ++no)
      atomicMax(&eb[ib + no * 16 + c], enc_safe(macc[no * 4 + r]));
  }
}

// ---------------- pairwise max pool + norms + bf16 splits --------------------
__global__ __launch_bounds__(256) void pool_kernel() {
  int node = blockIdx.x * 256 + threadIdx.x;  // < BATCH*N2
  int b = node >> 11;
  int m = node & (N2 - 1);
  const unsigned* e = g_ek1 + ((size_t)b * N1 + 2 * m) * HID;
  float* hr = g_h2 + (size_t)node * HID;
  float sq = 0.f;
  short s1l[HID], s2l[HID], s3l[HID];
#pragma unroll
  for (int d = 0; d < HID; ++d) {
    float mx = fmaxf(dec_safe(e[d]), dec_safe(e[HID + d]));
    hr[d] = mx;
    sq += mx * mx;
    split3(mx, s1l[d], s2l[d], s3l[d]);
  }
  store_frags(node, s1l, s2l, s3l);
  g_x2n2[node] = sq;
}

// ---------------- global max + output MLP -> FLOAT32 output ------------------
__global__ __launch_bounds__(64) void final_kernel(
    const float* __restrict__ wo1, const float* __restrict__ bo1,
    const float* __restrict__ wo2, const float* __restrict__ bo2,
    const float* __restrict__ wo3, const float* __restrict__ bo3,
    float* __restrict__ out) {
  __shared__ float g[HID];
  __shared__ float o1s[HID];
  __shared__ float o2s[32];
  int b = blockIdx.x;
  int t = threadIdx.x;  // 0..63
  const unsigned* e = g_ek2 + (size_t)b * N2 * HID;
  unsigned mk = 0u;
  for (int m = 0; m < N2; ++m) {
    unsigned q = e[(size_t)m * HID + t];
    mk = q > mk ? q : mk;
  }
  g[t] = dec_safe(mk);
  __syncthreads();
  {
    float a1 = bo1[t];
    for (int d = 0; d < HID; ++d) a1 += g[d] * wo1[d * HID + t];
    o1s[t] = eluf(a1);
  }
  __syncthreads();
  if (t < 32) {
    float a2 = bo2[t];
    for (int d = 0; d < HID; ++d) a2 += o1s[d] * wo2[d * 32 + t];
    o2s[t] = eluf(a2);
  }
  __syncthreads();
  if (t == 0) {
    float acc0 = bo3[0];
    float acc1 = bo3[1];
    for (int d = 0; d < 32; ++d) {
      acc0 += o2s[d] * wo3[d * 2 + 0];
      acc1 += o2s[d] * wo3[d * 2 + 1];
    }
    float met = fmaxf(acc0, 0.f) + log1pf(expf(-fabsf(acc0)));      // softplus
    float phi = 3.14159265358979f * (2.f / (1.f + expf(-acc1)) - 1.f);
    out[b * 2 + 0] = met;
    out[b * 2 + 1] = phi;
  }
}

extern "C" void kernel_launch(void* const* d_in, const int* in_sizes, int n_in,
                              void* d_out, int out_size, void* d_ws,
                              size_t ws_size, hipStream_t stream) {
  const float* x     = (const float*)d_in[0];
  const float* dnorm = (const float*)d_in[1];
  const float* w_in1 = (const float*)d_in[2];
  const float* b_in1 = (const float*)d_in[3];
  const float* w_in2 = (const float*)d_in[4];
  const float* b_in2 = (const float*)d_in[5];
  const float* w_c1a = (const float*)d_in[6];
  const float* b_c1a = (const float*)d_in[7];
  const float* w_c1b = (const float*)d_in[8];
  const float* b_c1b = (const float*)d_in[9];
  const float* w_c2a = (const float*)d_in[10];
  const float* b_c2a = (const float*)d_in[11];
  const float* w_c2b = (const float*)d_in[12];
  const float* b_c2b = (const float*)d_in[13];
  const float* w_o1  = (const float*)d_in[14];
  const float* b_o1  = (const float*)d_in[15];
  const float* w_o2  = (const float*)d_in[16];
  const float* b_o2  = (const float*)d_in[17];
  const float* w_o3  = (const float*)d_in[18];
  const float* b_o3  = (const float*)d_in[19];

  init_kernel<<<(BATCH * N1 * HID + BATCH * N2 * HID) / 4 / 256, 256, 0,
                stream>>>();
  wfrag_kernel<<<2, 256, 0, stream>>>(w_c1b, w_c2b);
  input_mlp<<<BATCH * N1 / 256, 256, 0, stream>>>(x, dnorm, w_in1, b_in1,
                                                  w_in2, b_in2);
  knn_kernel<0><<<8 * (N1 / 64), 256, 0, stream>>>();
  uv_kernel<<<8 * (N1 / 64), 256, 0, stream>>>(0, w_c1a, b_c1a);
  edge_kernel<0><<<8 * (N1 / 16), 64, 0, stream>>>(b_c1b);
  pool_kernel<<<BATCH * N2 / 256, 256, 0, stream>>>();
  knn_kernel<1><<<8 * (N2 / 64), 256, 0, stream>>>();
  uv_kernel<<<8 * (N2 / 64), 256, 0, stream>>>(1, w_c2a, b_c2a);
  edge_kernel<1><<<8 * (N2 / 16), 64, 0, stream>>>(b_c2b);
  final_kernel<<<BATCH, 64, 0, stream>>>(w_o1, b_o1, w_o2, b_o2, w_o3, b_o3,
                                         (float*)d_out);
}

// Round 21
// 638.347 us; speedup vs baseline: 1.1988x; 1.1988x over previous
//
#include <hip/hip_runtime.h>
#include <hip/hip_bf16.h>

#define BATCH 8
#define N1 4096
#define N2 2048
#define HID 64
#define KNN 8
#define INDIM 10

using u64 = unsigned long long;
using bf16 = __hip_bfloat16;
typedef __attribute__((ext_vector_type(8))) short short8;
typedef __attribute__((ext_vector_type(4))) float f32x4;

// Scratch in static device memory (~115 MB): d_ws size is not guaranteed.
// Every buffer is fully rewritten each call (or re-initialized by init_kernel).
__device__ __align__(256) float    g_h1[BATCH * N1 * HID];
__device__ __align__(256) float    g_h2[BATCH * N2 * HID];
__device__ __align__(256) float    g_x2n[BATCH * N1];
__device__ __align__(256) float    g_x2n2[BATCH * N2];
__device__ __align__(256) int      g_nbr[BATCH * N1 * KNN];
__device__ __align__(256) float    g_uu[BATCH * N1 * 96];
__device__ __align__(256) float    g_vv[BATCH * N1 * 96];
__device__ __align__(256) unsigned g_ek1[BATCH * N1 * HID];
__device__ __align__(256) unsigned g_ek2[BATCH * N2 * HID];
// 3-way bf16 split of h in MFMA FRAGMENT-MAJOR layout (kNN):
// [tile16][chunk(2)][q(4)][c(16)][j(8)] shorts; node i=tile*16+c.
__device__ __align__(256) short    g_f1[BATCH * N1 * HID];
__device__ __align__(256) short    g_f2[BATCH * N1 * HID];
__device__ __align__(256) short    g_f3[BATCH * N1 * HID];
// frag-major f32 copies of u,v for edge MFMA A-prep:
// [tile16][kc(3)][q(4)][c(16)][j(8)] floats, node = tile*16+c, kk=kc*32+q*8+j.
__device__ __align__(256) float    g_uf[BATCH * N1 * 96];
__device__ __align__(256) float    g_vf[BATCH * N1 * 96];
// 2-way bf16 split W2 fragments: [level][no(4)][kc(3)][lane(64)][j(8)]
__device__ __align__(256) short    g_wf1[2 * 4 * 3 * 64 * 8];
__device__ __align__(256) short    g_wf2[2 * 4 * 3 * 64 * 8];

__device__ __forceinline__ float eluf(float x) { return x > 0.f ? x : __expf(x) - 1.f; }
// order-isomorphic float->u32 encoding: a<b  <=>  enc(a)<enc(b) (unsigned)
__device__ __forceinline__ unsigned encf(float f) {
  unsigned u = __float_as_uint(f);
  return (u & 0x80000000u) ? ~u : (u | 0x80000000u);
}
__device__ __forceinline__ float decf(unsigned k) {
  unsigned u = (k & 0x80000000u) ? (k & 0x7FFFFFFFu) : ~k;
  return __uint_as_float(u);
}
// encf(-1.0f): ELU outputs are strictly > -1 => legal max-identity.
#define ENC_NEG1 0x407FFFFFu
__device__ __forceinline__ unsigned enc_safe(float v) {
  if (!(v == v)) return ENC_NEG1;
  return encf(v);
}
__device__ __forceinline__ float dec_safe(unsigned k) {
  float v = decf(k);
  if (!(v == v)) return -1.0f;
  return fminf(fmaxf(v, -3.0e38f), 3.0e38f);
}
// 3-way bf16 split: v ~= b1 + b2 + b3 (error ~2^-25 relative)
__device__ __forceinline__ void split3(float v, short& b1, short& b2, short& b3) {
  bf16 x1 = __float2bfloat16(v);
  float r1 = v - __bfloat162float(x1);
  bf16 x2 = __float2bfloat16(r1);
  float r2 = r1 - __bfloat162float(x2);
  bf16 x3 = __float2bfloat16(r2);
  b1 = *(short*)&x1; b2 = *(short*)&x2; b3 = *(short*)&x3;
}
// 2-way bf16 split
__device__ __forceinline__ void split2(float v, short& b1, short& b2) {
  bf16 x1 = __float2bfloat16(v);
  float r1 = v - __bfloat162float(x1);
  bf16 x2 = __float2bfloat16(r1);
  b1 = *(short*)&x1; b2 = *(short*)&x2;
}
// write one node's 64 splits into kNN fragment-major layout
__device__ __forceinline__ void store_frags(int node, const short* s1,
                                            const short* s2, const short* s3) {
  size_t tb = ((size_t)(node >> 4)) * 1024 + (node & 15) * 8;
#pragma unroll
  for (int chunk = 0; chunk < 2; ++chunk) {
#pragma unroll
    for (int q = 0; q < 4; ++q) {
      size_t a = tb + chunk * 512 + q * 128;
      int k = chunk * 32 + q * 8;
      *(short8*)(g_f1 + a) = *(const short8*)(s1 + k);
      *(short8*)(g_f2 + a) = *(const short8*)(s2 + k);
      *(short8*)(g_f3 + a) = *(const short8*)(s3 + k);
    }
  }
}
// elu(a+b) for 8 floats -> 2-way split short8 frags
__device__ __forceinline__ void tv_frag(float4 a0, float4 a1, float4 b0,
                                        float4 b1, short8& s1, short8& s2) {
  float v[8] = {a0.x + b0.x, a0.y + b0.y, a0.z + b0.z, a0.w + b0.w,
                a1.x + b1.x, a1.y + b1.y, a1.z + b1.z, a1.w + b1.w};
#pragma unroll
  for (int e = 0; e < 8; ++e) {
    float t = eluf(v[e]);
    short p1, p2;
    split2(t, p1, p2);
    s1[e] = p1; s2[e] = p2;
  }
}

// ---------------- init the scatter-max accumulators --------------------------
__global__ __launch_bounds__(256) void init_kernel() {
  int t = blockIdx.x * 256 + threadIdx.x;
  uint4 z = make_uint4(ENC_NEG1, ENC_NEG1, ENC_NEG1, ENC_NEG1);
  const int n1 = BATCH * N1 * HID / 4;
  if (t < n1) ((uint4*)g_ek1)[t] = z;
  else ((uint4*)g_ek2)[t - n1] = z;
}

// ---------------- W2 -> 2-way-split MFMA B-fragments (once per launch) -------
__global__ __launch_bounds__(256) void wfrag_kernel(const float* __restrict__ w1,
                                                    const float* __restrict__ w2) {
  int level = blockIdx.x;
  const float* w = level ? w2 : w1;
  for (int idx = threadIdx.x; idx < 6144; idx += 256) {
    int no = idx / 1536;
    int rem = idx - no * 1536;
    int kc = rem / 512;
    int rem2 = rem - kc * 512;
    int lane = rem2 >> 3;
    int j = rem2 & 7;
    int k = kc * 32 + (lane >> 4) * 8 + j;
    int o = no * 16 + (lane & 15);
    short b1, b2;
    split2(w[k * 64 + o], b1, b2);
    g_wf1[level * 6144 + idx] = b1;
    g_wf2[level * 6144 + idx] = b2;
  }
}

// ---------------- input MLP: x*norm -> 32 (elu) -> 64 (elu) + |h|^2 + splits -
__global__ __launch_bounds__(256) void input_mlp(
    const float* __restrict__ x, const float* __restrict__ norm,
    const float* __restrict__ w1g, const float* __restrict__ b1g,
    const float* __restrict__ w2g, const float* __restrict__ b2g) {
  __shared__ float sw1[320], sb1[32], sw2[2048], sb2[64], snorm[INDIM];
  int t = threadIdx.x;
  for (int q = t; q < 320; q += 256) sw1[q] = w1g[q];
  for (int q = t; q < 2048; q += 256) sw2[q] = w2g[q];
  if (t < 32) sb1[t] = b1g[t];
  if (t < 64) sb2[t] = b2g[t];
  if (t < INDIM) snorm[t] = norm[t];
  __syncthreads();
  int node = blockIdx.x * 256 + t;  // < BATCH*N1
  float xv[INDIM];
#pragma unroll
  for (int d = 0; d < INDIM; ++d)
    xv[d] = x[(size_t)node * INDIM + d] * snorm[d];
  float t1[32];
#pragma unroll
  for (int c = 0; c < 32; ++c) {
    float acc = sb1[c];
#pragma unroll
    for (int d = 0; d < INDIM; ++d) acc += xv[d] * sw1[d * 32 + c];
    t1[c] = eluf(acc);
  }
  float* hr = g_h1 + (size_t)node * HID;
  float sq = 0.f;
  short s1l[HID], s2l[HID], s3l[HID];
#pragma unroll
  for (int c = 0; c < HID; ++c) {
    float acc = sb2[c];
#pragma unroll
    for (int d = 0; d < 32; ++d) acc += t1[d] * sw2[d * HID + c];
    float v = eluf(acc);
    hr[c] = v;
    sq += v * v;
    split3(v, s1l[c], s2l[c], s3l[c]);
  }
  store_frags(node, s1l, s2l, s3l);
  g_x2n[node] = sq;
}

// ---------------- MFMA Gram-matrix kNN (k=8), u32-key bubble selection -------
// Best-known config (r17, 220us): 256-thread blocks, unsplit columns.
// Selection: key32 = (encf(dd)&0xFFFFFF00)|ct, unconditional 8-step
// v_min/v_max bubble; 16-lane exact merge via LDS (u64-lifted, tie->lowest j).
template <int LEVEL>
__global__ __launch_bounds__(256, 1) void knn_kernel() {
  constexpr int n = LEVEL ? N2 : N1;
  __shared__ unsigned lm[4][16][16][KNN];  // 32 KB
  int b = blockIdx.x & 7;             // XCD-friendly batch swizzle
  int rb = (blockIdx.x >> 3) * 64;    // block row base
  int t = threadIdx.x;
  int wv = t >> 6, lane = t & 63;
  int q = lane >> 4, c = lane & 15;
  int rbase = rb + wv * 16;           // wave's 16-row strip
  const float* __restrict__ x2b = (LEVEL ? g_x2n2 : g_x2n) + (size_t)b * n;
  size_t abase = ((size_t)((b * n + rbase) >> 4)) * 1024 + lane * 8;
  short8 A1a = *(const short8*)(g_f1 + abase);
  short8 A1b = *(const short8*)(g_f1 + abase + 512);
  short8 A2a = *(const short8*)(g_f2 + abase);
  short8 A2b = *(const short8*)(g_f2 + abase + 512);
  short8 A3a = *(const short8*)(g_f3 + abase);
  short8 A3b = *(const short8*)(g_f3 + abase + 512);
  float x2r[4];
#pragma unroll
  for (int r = 0; r < 4; ++r) x2r[r] = x2b[rbase + q * 4 + r];
  unsigned best[4][KNN];
#pragma unroll
  for (int r = 0; r < 4; ++r)
#pragma unroll
    for (int p = 0; p < KNN; ++p) best[r][p] = 0xFFFFFFFFu;
  size_t bb = ((size_t)(b * n) >> 4) * 1024 + lane * 8;
  for (int ct = 0; ct < n / 16; ++ct, bb += 1024) {
    int cb = ct * 16 + c;  // this lane's column
    short8 B1a = *(const short8*)(g_f1 + bb);
    short8 B1b = *(const short8*)(g_f1 + bb + 512);
    short8 B2a = *(const short8*)(g_f2 + bb);
    short8 B2b = *(const short8*)(g_f2 + bb + 512);
    short8 B3a = *(const short8*)(g_f3 + bb);
    short8 B3b = *(const short8*)(g_f3 + bb + 512);
    f32x4 acc0 = {0.f, 0.f, 0.f, 0.f};
    f32x4 acc1 = {0.f, 0.f, 0.f, 0.f};
    acc0 = __builtin_amdgcn_mfma_f32_16x16x32_bf16(A1a, B1a, acc0, 0, 0, 0);
    acc1 = __builtin_amdgcn_mfma_f32_16x16x32_bf16(A1b, B1b, acc1, 0, 0, 0);
    acc0 = __builtin_amdgcn_mfma_f32_16x16x32_bf16(A1a, B2a, acc0, 0, 0, 0);
    acc1 = __builtin_amdgcn_mfma_f32_16x16x32_bf16(A1b, B2b, acc1, 0, 0, 0);
    acc0 = __builtin_amdgcn_mfma_f32_16x16x32_bf16(A2a, B1a, acc0, 0, 0, 0);
    acc1 = __builtin_amdgcn_mfma_f32_16x16x32_bf16(A2b, B1b, acc1, 0, 0, 0);
    acc0 = __builtin_amdgcn_mfma_f32_16x16x32_bf16(A1a, B3a, acc0, 0, 0, 0);
    acc1 = __builtin_amdgcn_mfma_f32_16x16x32_bf16(A1b, B3b, acc1, 0, 0, 0);
    acc0 = __builtin_amdgcn_mfma_f32_16x16x32_bf16(A2a, B2a, acc0, 0, 0, 0);
    acc1 = __builtin_amdgcn_mfma_f32_16x16x32_bf16(A2b, B2b, acc1, 0, 0, 0);
    acc0 = __builtin_amdgcn_mfma_f32_16x16x32_bf16(A3a, B1a, acc0, 0, 0, 0);
    acc1 = __builtin_amdgcn_mfma_f32_16x16x32_bf16(A3b, B1b, acc1, 0, 0, 0);
    float x2c = x2b[cb];
#pragma unroll
    for (int r = 0; r < 4; ++r) {
      int i = rbase + q * 4 + r;
      float dd = x2r[r] + x2c - 2.f * (acc0[r] + acc1[r]);
      unsigned ck = (encf(dd) & 0xFFFFFF00u) | (unsigned)ct;
      ck = (cb == i) ? 0xFFFFFFFFu : ck;
#pragma unroll
      for (int p = 0; p < KNN; ++p) {
        unsigned nb = min(best[r][p], ck);
        ck = max(best[r][p], ck);
        best[r][p] = nb;
      }
    }
  }
#pragma unroll
  for (int r = 0; r < 4; ++r)
#pragma unroll
    for (int p = 0; p < KNN; ++p) lm[wv][q * 4 + r][c][p] = best[r][p];
  __syncthreads();
  if (t < 64) {
    int wv2 = t >> 4, r16 = t & 15;
    u64 fin[KNN];
#pragma unroll
    for (int p = 0; p < KNN; ++p) fin[p] = ((u64)lm[wv2][r16][0][p]) << 4;
    for (int c2 = 1; c2 < 16; ++c2) {
#pragma unroll
      for (int p = 0; p < KNN; ++p) {
        u64 ck = (((u64)lm[wv2][r16][c2][p]) << 4) | (unsigned)c2;
        if (ck < fin[KNN - 1]) {
#pragma unroll
          for (int p2 = 0; p2 < KNN; ++p2) {
            u64 ob = fin[p2];
            bool ex = ob < ck;
            fin[p2] = ex ? ob : ck;
            ck = ex ? ck : ob;
          }
        }
      }
    }
    int row = rb + wv2 * 16 + r16;
    int* ob = g_nbr + ((size_t)b * n + row) * KNN;
#pragma unroll
    for (int p = 0; p < KNN; ++p) {
      int j = (int)((fin[p] >> 4) & 255u) * 16 + (int)(fin[p] & 15u);
      ob[p] = j & (n - 1);
    }
  }
}

// ---------------- per-node u/v for EdgeConv layer-1 factorization ------------
__global__ __launch_bounds__(256) void uv_kernel(int level,
                                                 const float* __restrict__ w1g,
                                                 const float* __restrict__ b1g) {
  __shared__ float sw1[128 * 96];  // 48 KB
  __shared__ float sb1[96];
  int t = threadIdx.x;
  for (int q = t; q < 128 * 96; q += 256) sw1[q] = w1g[q];
  if (t < 96) sb1[t] = b1g[t];
  __syncthreads();
  const int n = level ? N2 : N1;
  const float* h = level ? g_h2 : g_h1;
  int b = blockIdx.x & 7;
  int nl = (blockIdx.x >> 3) * 64 + (t & 63);
  int c0 = (t >> 6) * 24;  // wave-uniform chunk
  size_t node = (size_t)b * n + nl;
  const float4* h4 = (const float4*)(h + node * HID);
  float hv[HID];
#pragma unroll
  for (int q = 0; q < 16; ++q) {
    float4 vv = h4[q];
    hv[4 * q] = vv.x; hv[4 * q + 1] = vv.y; hv[4 * q + 2] = vv.z; hv[4 * q + 3] = vv.w;
  }
  float ua[24], va[24];
#pragma unroll
  for (int c = 0; c < 24; ++c) { ua[c] = 0.f; va[c] = 0.f; }
  for (int d = 0; d < HID; ++d) {
    float hd = hv[d];
    const float* wt = sw1 + d * 96 + c0;        // wave-uniform -> broadcast
    const float* wb = sw1 + (HID + d) * 96 + c0;
#pragma unroll
    for (int c = 0; c < 24; ++c) {
      ua[c] += hd * wt[c];
      va[c] += hd * wb[c];
    }
  }
  float* ur = g_uu + node * 96 + c0;
  float* vr = g_vv + node * 96 + c0;
#pragma unroll
  for (int c = 0; c < 24; ++c) {
    float uval = ua[c] - va[c] + sb1[c0 + c];
    float vval = va[c];
    ur[c] = uval;
    vr[c] = vval;
    int kk = c0 + c;
    size_t fa = (node >> 4) * 1536 + (size_t)((kk >> 5) * 512 +
                ((kk >> 3) & 3) * 128 + (nl & 15) * 8 + (kk & 7));
    g_uf[fa] = uval;
    g_vf[fa] = vval;
  }
}

// ---------------- MFMA edge messages + max scatter (r17 config) --------------
// Wave = 16 nodes (one frag tile), 4 waves/block: W-frags hoisted once per
// 64 nodes and intra-block wave overlap hides the neighbor-gather latency.
// (r20's 1-wave split re-loaded W-frags 4x and regressed ~100us.)
template <int LEVEL>
__global__ __launch_bounds__(256, 1) void edge_kernel(
    const float* __restrict__ b2g) {
  constexpr int n = LEVEL ? N2 : N1;
  unsigned* ekey = LEVEL ? g_ek2 : g_ek1;
  int b = blockIdx.x & 7;  // XCD swizzle
  int t = threadIdx.x;
  int wv = t >> 6, lane = t & 63;
  int q = lane >> 4, c = lane & 15;
  int base16 = (blockIdx.x >> 3) * 64 + wv * 16;
  int node_c = base16 + c;
  const int* nbb = g_nbr + (size_t)b * n * KNN;
  const float* ub = g_uu + (size_t)b * n * 96;
  const float* vb = g_vv + (size_t)b * n * 96;
  size_t ftile = ((size_t)(b * n + base16) >> 4) * 1536;
  unsigned* eb = ekey + (size_t)b * n * HID;
  short8 W1f[4][3], W2f[4][3];
#pragma unroll
  for (int no = 0; no < 4; ++no)
#pragma unroll
    for (int kc = 0; kc < 3; ++kc) {
      int off = LEVEL * 6144 + ((no * 3 + kc) * 64 + lane) * 8;
      W1f[no][kc] = *(const short8*)(g_wf1 + off);
      W2f[no][kc] = *(const short8*)(g_wf2 + off);
    }
  float biasv[4];
#pragma unroll
  for (int no = 0; no < 4; ++no) biasv[no] = b2g[no * 16 + c];
  float macc[16];
#pragma unroll
  for (int e = 0; e < 16; ++e) macc[e] = -1.0f;
  for (int slot = 0; slot < KNN; ++slot) {
    int jn = nbb[(size_t)node_c * KNN + slot] & (n - 1);
    short8 t1[3], t2[3], r1[3], r2[3];
#pragma unroll
    for (int kc = 0; kc < 3; ++kc) {
      size_t fo = ftile + kc * 512 + lane * 8;
      float4 su0 = *(const float4*)(g_uf + fo);
      float4 su1 = *(const float4*)(g_uf + fo + 4);
      float4 sv0 = *(const float4*)(g_vf + fo);
      float4 sv1 = *(const float4*)(g_vf + fo + 4);
      size_t go = (size_t)jn * 96 + kc * 32 + q * 8;
      float4 gv0 = *(const float4*)(vb + go);
      float4 gv1 = *(const float4*)(vb + go + 4);
      float4 gu0 = *(const float4*)(ub + go);
      float4 gu1 = *(const float4*)(ub + go + 4);
      tv_frag(su0, su1, gv0, gv1, t1[kc], t2[kc]);   // fwd: u_i + v_j
      tv_frag(gu0, gu1, sv0, sv1, r1[kc], r2[kc]);   // rev: u_j + v_i
    }
    f32x4 aF[4], aR[4];
#pragma unroll
    for (int no = 0; no < 4; ++no) {
      aF[no] = (f32x4){0.f, 0.f, 0.f, 0.f};
      aR[no] = (f32x4){0.f, 0.f, 0.f, 0.f};
    }
#pragma unroll
    for (int no = 0; no < 4; ++no)
#pragma unroll
      for (int kc = 0; kc < 3; ++kc) {
        aF[no] = __builtin_amdgcn_mfma_f32_16x16x32_bf16(t1[kc], W1f[no][kc], aF[no], 0, 0, 0);
        aF[no] = __builtin_amdgcn_mfma_f32_16x16x32_bf16(t2[kc], W1f[no][kc], aF[no], 0, 0, 0);
        aF[no] = __builtin_amdgcn_mfma_f32_16x16x32_bf16(t1[kc], W2f[no][kc], aF[no], 0, 0, 0);
        aR[no] = __builtin_amdgcn_mfma_f32_16x16x32_bf16(r1[kc], W1f[no][kc], aR[no], 0, 0, 0);
        aR[no] = __builtin_amdgcn_mfma_f32_16x16x32_bf16(r2[kc], W1f[no][kc], aR[no], 0, 0, 0);
        aR[no] = __builtin_amdgcn_mfma_f32_16x16x32_bf16(r1[kc], W2f[no][kc], aR[no], 0, 0, 0);
      }
#pragma unroll
    for (int r = 0; r < 4; ++r) {
      int jr = nbb[(size_t)(base16 + q * 4 + r) * KNN + slot] & (n - 1);
#pragma unroll
      for (int no = 0; no < 4; ++no) {
        float mv = eluf(aR[no][r] + biasv[no]);
        atomicMax(&eb[(size_t)jr * HID + no * 16 + c], enc_safe(mv));
      }
    }
#pragma unroll
    for (int no = 0; no < 4; ++no)
#pragma unroll
      for (int r = 0; r < 4; ++r)
        macc[no * 4 + r] = fmaxf(macc[no * 4 + r], eluf(aF[no][r] + biasv[no]));
  }
#pragma unroll
  for (int r = 0; r < 4; ++r) {
    size_t ib = (size_t)(base16 + q * 4 + r) * HID;
#pragma unroll
    for (int no = 0; no < 4; ++no)
      atomicMax(&eb[ib + no * 16 + c], enc_safe(macc[no * 4 + r]));
  }
}

// ---------------- pairwise max pool + norms + bf16 splits --------------------
__global__ __launch_bounds__(256) void pool_kernel() {
  int node = blockIdx.x * 256 + threadIdx.x;  // < BATCH*N2
  int b = node >> 11;
  int m = node & (N2 - 1);
  const unsigned* e = g_ek1 + ((size_t)b * N1 + 2 * m) * HID;
  float* hr = g_h2 + (size_t)node * HID;
  float sq = 0.f;
  short s1l[HID], s2l[HID], s3l[HID];
#pragma unroll
  for (int d = 0; d < HID; ++d) {
    float mx = fmaxf(dec_safe(e[d]), dec_safe(e[HID + d]));
    hr[d] = mx;
    sq += mx * mx;
    split3(mx, s1l[d], s2l[d], s3l[d]);
  }
  store_frags(node, s1l, s2l, s3l);
  g_x2n2[node] = sq;
}

// ---------------- global max + output MLP -> FLOAT32 output ------------------
__global__ __launch_bounds__(64) void final_kernel(
    const float* __restrict__ wo1, const float* __restrict__ bo1,
    const float* __restrict__ wo2, const float* __restrict__ bo2,
    const float* __restrict__ wo3, const float* __restrict__ bo3,
    float* __restrict__ out) {
  __shared__ float g[HID];
  __shared__ float o1s[HID];
  __shared__ float o2s[32];
  int b = blockIdx.x;
  int t = threadIdx.x;  // 0..63
  const unsigned* e = g_ek2 + (size_t)b * N2 * HID;
  unsigned mk = 0u;
  for (int m = 0; m < N2; ++m) {
    unsigned q = e[(size_t)m * HID + t];
    mk = q > mk ? q : mk;
  }
  g[t] = dec_safe(mk);
  __syncthreads();
  {
    float a1 = bo1[t];
    for (int d = 0; d < HID; ++d) a1 += g[d] * wo1[d * HID + t];
    o1s[t] = eluf(a1);
  }
  __syncthreads();
  if (t < 32) {
    float a2 = bo2[t];
    for (int d = 0; d < HID; ++d) a2 += o1s[d] * wo2[d * 32 + t];
    o2s[t] = eluf(a2);
  }
  __syncthreads();
  if (t == 0) {
    float acc0 = bo3[0];
    float acc1 = bo3[1];
    for (int d = 0; d < 32; ++d) {
      acc0 += o2s[d] * wo3[d * 2 + 0];
      acc1 += o2s[d] * wo3[d * 2 + 1];
    }
    float met = fmaxf(acc0, 0.f) + log1pf(expf(-fabsf(acc0)));      // softplus
    float phi = 3.14159265358979f * (2.f / (1.f + expf(-acc1)) - 1.f);
    out[b * 2 + 0] = met;
    out[b * 2 + 1] = phi;
  }
}

extern "C" void kernel_launch(void* const* d_in, const int* in_sizes, int n_in,
                              void* d_out, int out_size, void* d_ws,
                              size_t ws_size, hipStream_t stream) {
  const float* x     = (const float*)d_in[0];
  const float* dnorm = (const float*)d_in[1];
  const float* w_in1 = (const float*)d_in[2];
  const float* b_in1 = (const float*)d_in[3];
  const float* w_in2 = (const float*)d_in[4];
  const float* b_in2 = (const float*)d_in[5];
  const float* w_c1a = (const float*)d_in[6];
  const float* b_c1a = (const float*)d_in[7];
  const float* w_c1b = (const float*)d_in[8];
  const float* b_c1b = (const float*)d_in[9];
  const float* w_c2a = (const float*)d_in[10];
  const float* b_c2a = (const float*)d_in[11];
  const float* w_c2b = (const float*)d_in[12];
  const float* b_c2b = (const float*)d_in[13];
  const float* w_o1  = (const float*)d_in[14];
  const float* b_o1  = (const float*)d_in[15];
  const float* w_o2  = (const float*)d_in[16];
  const float* b_o2  = (const float*)d_in[17];
  const float* w_o3  = (const float*)d_in[18];
  const float* b_o3  = (const float*)d_in[19];

  init_kernel<<<(BATCH * N1 * HID + BATCH * N2 * HID) / 4 / 256, 256, 0,
                stream>>>();
  wfrag_kernel<<<2, 256, 0, stream>>>(w_c1b, w_c2b);
  input_mlp<<<BATCH * N1 / 256, 256, 0, stream>>>(x, dnorm, w_in1, b_in1,
                                                  w_in2, b_in2);
  knn_kernel<0><<<8 * (N1 / 64), 256, 0, stream>>>();
  uv_kernel<<<8 * (N1 / 64), 256, 0, stream>>>(0, w_c1a, b_c1a);
  edge_kernel<0><<<8 * (N1 / 64), 256, 0, stream>>>(b_c1b);
  pool_kernel<<<BATCH * N2 / 256, 256, 0, stream>>>();
  knn_kernel<1><<<8 * (N2 / 64), 256, 0, stream>>>();
  uv_kernel<<<8 * (N2 / 64), 256, 0, stream>>>(1, w_c2a, b_c2a);
  edge_kernel<1><<<8 * (N2 / 64), 256, 0, stream>>>(b_c2b);
  final_kernel<<<BATCH, 64, 0, stream>>>(w_o1, b_o1, w_o2, b_o2, w_o3, b_o3,
                                         (float*)d_out);
}